// Round 15
// baseline (263.367 us; speedup 1.0000x reference)
//
#include <hip/hip_runtime.h>

#define B_   32
#define L_   200
#define DIM_ 36
#define ET_  128
#define NH_  64
#define SD_  9
#define NC_  2

// element offsets within d_out (float32)
#define O_TE   0
#define O_T1   147456
#define O_LG   294912
#define O_SXG  294976
#define O_SOUT 336448
#define O_QP   377920

typedef __fp16 half_t;
typedef __attribute__((ext_vector_type(2))) __fp16 half2_t;

__device__ __forceinline__ float sigm(float x) { return 1.f / (1.f + expf(-x)); }
__device__ __forceinline__ float fsigm(float x) {
  return __builtin_amdgcn_rcpf(1.f + __expf(-x));
}
__device__ __forceinline__ float ftanh(float x) {
  return 2.f * __builtin_amdgcn_rcpf(1.f + __expf(-2.f * x)) - 1.f;
}
__device__ __forceinline__ half2_t f2h2(float a, float b) {
  return __builtin_amdgcn_cvt_pkrtz(a, b);
}
__device__ __forceinline__ float dot2acc(half2_t w, half2_t h, float acc) {
#if __has_builtin(__builtin_amdgcn_fdot2)
  return __builtin_amdgcn_fdot2(w, h, acc, false);
#else
  return acc + (float)w.x * (float)h.x + (float)w.y * (float)h.y;
#endif
}

// ---------------------------------------------------------------------------
// K1 (k_pre2): merged k_pre + k_qm2 (R14: ~9us/launch overhead).
//  blocks 0..127: qm2[q] computed directly, no cross-block dep:
//    uq[i] = e_q[q]·qw[i,:] + qb[i]; qm2[q][e] = uq·kw[:,e] / sqrt(128)
//  blocks 128..159: sx_g[b] + xmean[b]  (b = blk-128)
__global__ __launch_bounds__(256) void k_pre2(
    const float* __restrict__ qw, const float* __restrict__ kw,
    const float* __restrict__ qb, const float* __restrict__ qp,
    const float* __restrict__ pw, const float* __restrict__ pb,
    const float* __restrict__ tlw, const float* __restrict__ tlb,
    const float* __restrict__ x, float* __restrict__ qm2,
    float* __restrict__ xmean, float* __restrict__ out) {
  int blk = blockIdx.x, t = threadIdx.x;
  if (blk < 128) {
    __shared__ float eq[128];
    __shared__ float uq[128];
    int q = blk;
    if (t < 128) {
      float tt = qp[q];
      eq[t] = (t == 0) ? tt * tlw[0] + tlb[0]
                       : __sinf(tt * pw[t - 1] + pb[t - 1]);
    }
    __syncthreads();
    if (t < 128) {
      const float4* qw4 = (const float4*)(qw + (size_t)t * 128);
      float a = qb[t];
      #pragma unroll 8
      for (int c = 0; c < 32; c++) {
        float4 w = qw4[c];
        a += eq[4 * c] * w.x + eq[4 * c + 1] * w.y +
             eq[4 * c + 2] * w.z + eq[4 * c + 3] * w.w;
      }
      uq[t] = a;
    }
    __syncthreads();
    if (t < 128) {
      float a = 0.f;
      #pragma unroll 8
      for (int i = 0; i < 128; i++) a += uq[i] * kw[i * 128 + t];
      qm2[q * 128 + t] = a * 0.088388347648318447f;
      if (q == 0) out[O_QP + t] = qp[t];
    }
    return;
  }
  int b = blk - 128;
  __shared__ __align__(16) float sxs[L_][76];
  const float4* xsrc = (const float4*)(x + (size_t)b * L_ * 72);
  for (int idx = t; idx < L_ * 18; idx += 256) {
    int l = idx / 18, c = idx % 18;
    ((float4*)&sxs[l][0])[c] = xsrc[l * 18 + c];
  }
  __syncthreads();
  if (t < 72) {
    float s = 0.f;
    #pragma unroll 8
    for (int l = 0; l < L_; l++) s += sxs[l][t];
    xmean[b * 72 + t] = s * (1.0f / L_);
  }
  for (int idx = t; idx < DIM_ * DIM_; idx += 256) {
    int d = idx / DIM_, e = idx % DIM_;
    float s = 0.f;
    #pragma unroll 8
    for (int l = 0; l < L_; l++) s += sxs[l][d] * sxs[l][e];
    out[O_SXG + (size_t)b * DIM_ * DIM_ + idx] = rintf(sigm(s));
  }
}

// ---------------------------------------------------------------------------
// K2 (k_attn v5): R14's 1024-thread v4 + P8: GRU input-gates (gi) computed
// here (the block already holds its 16 out_te rows) and written to ws_gis.
// wih staged with stride-37 pad (t*36 stride would be 8-way bank conflict).
__global__ __launch_bounds__(1024, 1) void k_attn(
    const float* __restrict__ qm, const float* __restrict__ ts,
    const float* __restrict__ pw, const float* __restrict__ pb,
    const float* __restrict__ tlw, const float* __restrict__ tlb,
    const float* __restrict__ x, const int* __restrict__ rm,
    const float* __restrict__ xmean, const float* __restrict__ ow,
    const float* __restrict__ ob, const float* __restrict__ wih,
    const float* __restrict__ bih, const float* __restrict__ bhh,
    float* __restrict__ gis, float* __restrict__ out) {
  __shared__ __align__(16) char Abuf[103936];   // ks / wsh2 -> wihs+ote_t
  __shared__ __align__(16) float qs[16][128];
  __shared__ __align__(16) float sc[16][200];
  __shared__ __align__(16) float owsh[DIM_][72];
  float*   ksA  = (float*)Abuf;                       // [200][128] swizzled
  half2_t* wsh2 = (half2_t*)Abuf;                     // [200][72] f16x2
  float*   wihs = (float*)Abuf;                       // [192][37] (post-P5)
  float*   ote_t = (float*)(Abuf + 28416);            // [16][36]  (post-P5)
  float*   sums = (float*)(Abuf + 57600);             // [4][16][144]
  float*   ofr  = (float*)(Abuf + 57600 + 36864);     // [16][144]

  int b = blockIdx.x >> 3;
  int q0 = (blockIdx.x & 7) << 4;
  int tid = threadIdx.x;

  // P0: stage q-tile, ow, and swizzled key embeddings
  const float4* qsrc = (const float4*)(qm + q0 * ET_);
  for (int i = tid; i < 16 * 32; i += 1024) ((float4*)qs)[i] = qsrc[i];
  const float4* owsrc = (const float4*)ow;
  for (int i = tid; i < DIM_ * 18; i += 1024) ((float4*)owsh)[i] = owsrc[i];
  {
    float tl_w = tlw[0], tl_b = tlb[0];
    const float* tsb = ts + b * L_;
    for (int i = tid; i < L_ * 128; i += 1024) {
      int l = i >> 7, j = i & 127;
      float t = tsb[l];
      float e = (j == 0) ? t * tl_w + tl_b : __sinf(t * pw[j - 1] + pb[j - 1]);
      int blkj = (j >> 2) ^ ((l >> 2) & 7);
      ksA[(l << 7) + (blkj << 2) + (j & 3)] = e;
    }
  }
  __syncthreads();

  // P2: scores -- 16 waves = 8 q-pairs x 2 l-halves; 2 l per lane
  {
    int w = tid >> 6, lg = tid & 63;
    int qp2 = w >> 1;
    int lh = w & 1;
    float acc[2][2];
    #pragma unroll
    for (int i = 0; i < 2; i++)
      #pragma unroll
      for (int j = 0; j < 2; j++) acc[i][j] = 0.f;
    const float4* ks4 = (const float4*)ksA;
    const float4* qs4 = (const float4*)qs;
    int lbase = 100 * lh + 2 * lg;
    int swz0 = (lbase >> 2) & 7;
    int swz1 = ((lbase + 1) >> 2) & 7;
    #pragma unroll 4
    for (int d4 = 0; d4 < 32; d4++) {
      float4 kv[2];
      {
        int l0c = (lbase < 100 * lh + 100) ? lbase : (100 * lh + 99);
        int l1c = (lbase + 1 < 100 * lh + 100) ? lbase + 1 : (100 * lh + 99);
        kv[0] = ks4[(l0c << 5) + (d4 ^ swz0)];
        kv[1] = ks4[(l1c << 5) + (d4 ^ swz1)];
      }
      #pragma unroll
      for (int i = 0; i < 2; i++) {
        float4 qv = qs4[(2 * qp2 + i) * 32 + d4];
        #pragma unroll
        for (int j = 0; j < 2; j++)
          acc[i][j] += qv.x * kv[j].x + qv.y * kv[j].y +
                       qv.z * kv[j].z + qv.w * kv[j].w;
      }
    }
    if (2 * lg < 100) {
      #pragma unroll
      for (int i = 0; i < 2; i++) {
        float2 v = {acc[i][0], acc[i][1]};
        *((float2*)(&sc[2 * qp2 + i][lbase])) = v;
      }
    }
  }
  __syncthreads();

  // P3: rowmax + exp in place (64 lanes per q-row)
  {
    int qi = tid >> 6, li = tid & 63;
    float m = -1e30f;
    for (int l = li; l < L_; l += 64) m = fmaxf(m, sc[qi][l]);
    #pragma unroll
    for (int off = 32; off >= 1; off >>= 1) m = fmaxf(m, __shfl_xor(m, off));
    for (int l = li; l < L_; l += 64) sc[qi][l] = __expf(sc[qi][l] - m);
  }

  // P4: build W f16 into the (dead) ks region
  {
    const float2* xb2 = (const float2*)(x + (size_t)b * L_ * 72);
    const int* rmb = rm + b * L_;
    for (int i = tid; i < L_ * 72; i += 1024) {
      int l = i / 72, c2 = i % 72;
      int seg = c2 / 18, fh = c2 % 18;
      float2 v = xb2[l * 36 + fh];
      float2 o = xb2[l * 36 + 18 + fh];
      float rr = (float)rmb[l];
      float w0, w1;
      if (seg == 0)      { w0 = o.x * v.x;      w1 = o.y * v.y; }
      else if (seg == 1) { w0 = o.x;            w1 = o.y; }
      else if (seg == 2) { w0 = o.x * v.x * rr; w1 = o.y * v.y * rr; }
      else               { w0 = o.x * rr;       w1 = o.y * rr; }
      wsh2[l * 72 + c2] = f2h2(w0, w1);
    }
  }
  __syncthreads();

  // P5: weight sums, l split 4 ways (partials in sums[4][16][144])
  {
    int quarter = tid >> 8, tt = tid & 255;
    int qi = tt >> 4, li = tt & 15;
    int l0 = quarter * 50;
    float accA[8], accB[8];
    #pragma unroll
    for (int k = 0; k < 8; k++) { accA[k] = 0.f; accB[k] = 0.f; }
    const float4* wA = (const float4*)wsh2;
    #pragma unroll 2
    for (int l = l0; l < l0 + 50; l++) {
      float ev = sc[qi][l];
      float4 wa = wA[l * 18 + li];
      union { float f; half2_t h; } u0, u1, u2, u3;
      u0.f = wa.x; u1.f = wa.y; u2.f = wa.z; u3.f = wa.w;
      accA[0] += ev * (float)u0.h.x; accA[1] += ev * (float)u0.h.y;
      accA[2] += ev * (float)u1.h.x; accA[3] += ev * (float)u1.h.y;
      accA[4] += ev * (float)u2.h.x; accA[5] += ev * (float)u2.h.y;
      accA[6] += ev * (float)u3.h.x; accA[7] += ev * (float)u3.h.y;
      if (li < 2) {
        float4 wb = wA[l * 18 + 16 + li];
        union { float f; half2_t h; } b0, b1, b2, b3;
        b0.f = wb.x; b1.f = wb.y; b2.f = wb.z; b3.f = wb.w;
        accB[0] += ev * (float)b0.h.x; accB[1] += ev * (float)b0.h.y;
        accB[2] += ev * (float)b1.h.x; accB[3] += ev * (float)b1.h.y;
        accB[4] += ev * (float)b2.h.x; accB[5] += ev * (float)b2.h.y;
        accB[6] += ev * (float)b3.h.x; accB[7] += ev * (float)b3.h.y;
      }
    }
    float* sq = sums + quarter * 2304 + qi * 144;
    float4* sA = (float4*)(sq + 8 * li);
    sA[0] = make_float4(accA[0], accA[1], accA[2], accA[3]);
    sA[1] = make_float4(accA[4], accA[5], accA[6], accA[7]);
    if (li < 2) {
      float4* sB = (float4*)(sq + 128 + 8 * li);
      sB[0] = make_float4(accB[0], accB[1], accB[2], accB[3]);
      sB[1] = make_float4(accB[4], accB[5], accB[6], accB[7]);
    }
  }
  __syncthreads();

  // P6: combine quarters + divisions + fallback; ALSO stage wih (region dead)
  const float* xm = xmean + b * 72;
  for (int idx = tid; idx < 192 * 36; idx += 1024) {
    int r = idx / 36, d = idx % 36;
    wihs[r * 37 + d] = wih[idx];
  }
  for (int idx = tid; idx < 16 * DIM_; idx += 1024) {
    int qq = idx / DIM_, j = idx % DIM_;
    const float* s0 = sums + qq * 144;
    const float* s1 = s0 + 2304;
    const float* s2 = s1 + 2304;
    const float* s3 = s2 + 2304;
    float numA = (s0[j] + s1[j]) + (s2[j] + s3[j]);
    float denA = (s0[36 + j] + s1[36 + j]) + (s2[36 + j] + s3[36 + j]);
    float numB = (s0[72 + j] + s1[72 + j]) + (s2[72 + j] + s3[72 + j]);
    float denB = (s0[108 + j] + s1[108 + j]) + (s2[108 + j] + s3[108 + j]);
    float al, ah, bl, bh;
    if (denA > 0.f) { al = numA / denA; ah = 1.f; }
    else            { al = xm[j];       ah = xm[36 + j]; }
    if (denB > 0.f) { bl = numB / denB; bh = 1.f; }
    else            { bl = xm[j];       bh = xm[36 + j]; }
    float* oq = ofr + qq * 144;
    oq[j] = al;      oq[36 + j] = ah;
    oq[72 + j] = bl; oq[108 + j] = bh;
  }
  __syncthreads();

  // P7: output projection; v==0 results also cached to ote_t for P8
  for (int idx = tid; idx < 16 * 72; idx += 1024) {
    int qq = idx / 72, t = idx % 72;
    int v = t / DIM_, i2 = t % DIM_;
    const float4* o4 = (const float4*)(ofr + qq * 144 + v * 72);
    const float4* w4 = (const float4*)(owsh[i2]);
    float a = ob[i2];
    #pragma unroll
    for (int d4 = 0; d4 < 18; d4++) {
      float4 ov = o4[d4], wv = w4[d4];
      a += ov.x * wv.x + ov.y * wv.y + ov.z * wv.z + ov.w * wv.w;
    }
    size_t off = ((size_t)b * ET_ + q0 + qq) * DIM_ + i2;
    out[(v == 0 ? O_TE : O_T1) + off] = a;
    if (v == 0) ote_t[qq * 36 + i2] = a;
  }
  __syncthreads();

  // P8: gi[qq][t] = bih[t] (+bhh[t] for r/z) + ote_t[qq]·wihs[t] -> ws_gis
  for (int idx = tid; idx < 16 * 192; idx += 1024) {
    int qq = idx / 192, tt = idx % 192;
    const float* wr = wihs + tt * 37;
    const float* orow = ote_t + qq * 36;   // broadcast (qq wave-uniform-ish)
    float a = bih[tt] + ((tt < 2 * NH_) ? bhh[tt] : 0.f);
    #pragma unroll 6
    for (int d = 0; d < 36; d++) a += orow[d] * wr[d];
    gis[((size_t)b * ET_ + q0 + qq) * 192 + tt] = a;
  }
}

// ---------------------------------------------------------------------------
// K3 (k_sg): blocks 0..31: sout(b); blocks 32..63: GRU v8 (b = blk-32).
// GRU v8 = R12's v6 scan (best measured; R13: readlane is 2x worse than the
// LDS broadcast round-trip) with phase 1 REMOVED (gi precomputed by k_attn
// P8 into ws_gis) and gi read from global with depth-2 register prefetch
// (HBM ~900cy < 2 steps).
__global__ __launch_bounds__(256, 1) void k_sg(
    const float* __restrict__ out_ro, const float* __restrict__ gis,
    const float* __restrict__ whh, const float* __restrict__ bhh,
    float* __restrict__ hfin, float* __restrict__ out) {
  __shared__ __align__(16) float ote_s[ET_][DIM_];  // sout branch
  __shared__ __align__(16) half2_t hpk[NH_ / 2];    // packed f16 h
  int blk = blockIdx.x, t = threadIdx.x;

  if (blk < 32) {
    int b = blk;
    const float4* osrc = (const float4*)(out_ro + O_TE + (size_t)b * ET_ * DIM_);
    for (int idx = t; idx < ET_ * 9; idx += 256)
      ((float4*)&ote_s[0][0])[idx] = osrc[idx];
    __syncthreads();
    for (int idx = t; idx < DIM_ * DIM_; idx += 256) {
      int d = idx / DIM_, e = idx % DIM_;
      float s = 0.f;
      #pragma unroll 8
      for (int q = 0; q < ET_; q++) s += ote_s[q][d] * ote_s[q][e];
      out[O_SOUT + (size_t)b * DIM_ * DIM_ + idx] = sigm(s);
    }
    return;
  }

  if (t >= 64) return;  // single wave does the scan
  int b = blk - 32;
  const float* gb = gis + (size_t)b * ET_ * 192;

  // pack whh rows t, 64+t, 128+t into f16 (32 half2 each = 96 VGPRs)
  half2_t wr[32], wz[32], wn[32];
  {
    const float2* r0 = (const float2*)(whh + (size_t)t * NH_);
    const float2* r1 = (const float2*)(whh + (size_t)(NH_ + t) * NH_);
    const float2* r2 = (const float2*)(whh + (size_t)(2 * NH_ + t) * NH_);
    #pragma unroll
    for (int c = 0; c < 32; c++) {
      float2 a = r0[c], bb = r1[c], cc = r2[c];
      wr[c] = f2h2(a.x, a.y);
      wz[c] = f2h2(bb.x, bb.y);
      wn[c] = f2h2(cc.x, cc.y);
    }
  }
  float bh_n = bhh[2 * NH_ + t];

  // depth-2 gi prefetch
  float pr[2], pz[2], pn[2];
  pr[0] = gb[t];       pz[0] = gb[64 + t];       pn[0] = gb[128 + t];
  pr[1] = gb[192 + t]; pz[1] = gb[192 + 64 + t]; pn[1] = gb[192 + 128 + t];

  float h = 0.f;
  ((half_t*)hpk)[t] = (half_t)0.f;
  for (int q = 0; q < ET_; q++) {
    int s = q & 1;
    float gi_r = pr[s], gi_z = pz[s], gi_n = pn[s];
    if (q + 2 < ET_) {
      const float* g2 = gb + (q + 2) * 192;
      pr[s] = g2[t]; pz[s] = g2[64 + t]; pn[s] = g2[128 + t];
    }
    float ar = 0.f, az = 0.f, an = 0.f;
    const float4* hp4 = (const float4*)hpk;
    #pragma unroll
    for (int c4 = 0; c4 < 8; c4++) {
      float4 hv = hp4[c4];  // broadcast b128 (all lanes same addr)
      union { float f; half2_t h; } u0, u1, u2, u3;
      u0.f = hv.x; u1.f = hv.y; u2.f = hv.z; u3.f = hv.w;
      int c = c4 * 4;
      ar = dot2acc(wr[c + 0], u0.h, ar);
      az = dot2acc(wz[c + 0], u0.h, az);
      an = dot2acc(wn[c + 0], u0.h, an);
      ar = dot2acc(wr[c + 1], u1.h, ar);
      az = dot2acc(wz[c + 1], u1.h, az);
      an = dot2acc(wn[c + 1], u1.h, an);
      ar = dot2acc(wr[c + 2], u2.h, ar);
      az = dot2acc(wz[c + 2], u2.h, az);
      an = dot2acc(wn[c + 2], u2.h, an);
      ar = dot2acc(wr[c + 3], u3.h, ar);
      az = dot2acc(wz[c + 3], u3.h, az);
      an = dot2acc(wn[c + 3], u3.h, an);
    }
    float r = fsigm(gi_r + ar);
    float z = fsigm(gi_z + az);
    float n = ftanh(gi_n + r * (an + bh_n));
    h = n + z * (h - n);
    ((half_t*)hpk)[t] = (half_t)h;  // same-wave order: visible next iter
  }
  hfin[b * NH_ + t] = h;
}

// ---------------------------------------------------------------------------
// K4: classifier head: st, concat, c1, batchnorm(batch), gelu, c2 -> logits
__global__ __launch_bounds__(256) void k_cls(
    const float* __restrict__ hfin, const float* __restrict__ si,
    const float* __restrict__ stw, const float* __restrict__ stb,
    const float* __restrict__ c1w, const float* __restrict__ c1b,
    const float* __restrict__ bng, const float* __restrict__ bnb,
    const float* __restrict__ c2w, const float* __restrict__ c2b,
    float* __restrict__ out) {
  __shared__ float cin[B_][72];
  __shared__ float z1[B_][72];
  __shared__ float zg[B_][72];
  int t = threadIdx.x;
  for (int idx = t; idx < B_ * 8; idx += 256) {
    int b = idx / 8, j = idx % 8;
    float acc = stb[j];
    #pragma unroll
    for (int d = 0; d < SD_; d++) acc += si[b * SD_ + d] * stw[j * SD_ + d];
    cin[b][NH_ + j] = acc;
  }
  for (int idx = t; idx < B_ * NH_; idx += 256)
    cin[idx / NH_][idx % NH_] = hfin[idx];
  __syncthreads();
  for (int idx = t; idx < B_ * 72; idx += 256) {
    int b = idx / 72, j = idx % 72;
    float acc = c1b[j];
    #pragma unroll 8
    for (int d = 0; d < 72; d++) acc += cin[b][d] * c1w[j * 72 + d];
    z1[b][j] = acc;
  }
  __syncthreads();
  if (t < 72) {
    float mu = 0.f;
    for (int b = 0; b < B_; b++) mu += z1[b][t];
    mu *= (1.f / B_);
    float vv = 0.f;
    for (int b = 0; b < B_; b++) { float d = z1[b][t] - mu; vv += d * d; }
    vv *= (1.f / B_);
    float inv = 1.f / sqrtf(vv + 1e-5f);
    float g = bng[t], bb = bnb[t];
    for (int b = 0; b < B_; b++) {
      float zn = (z1[b][t] - mu) * inv * g + bb;
      zg[b][t] = 0.5f * zn * (1.f + erff(zn * 0.70710678118654752f));
    }
  }
  __syncthreads();
  for (int idx = t; idx < B_ * NC_; idx += 256) {
    int b = idx / NC_, c = idx % NC_;
    float acc = c2b[c];
    #pragma unroll 8
    for (int d = 0; d < 72; d++) acc += zg[b][d] * c2w[c * 72 + d];
    out[O_LG + idx] = acc;
  }
}

// ---------------------------------------------------------------------------
extern "C" void kernel_launch(void* const* d_in, const int* in_sizes, int n_in,
                              void* d_out, int out_size, void* d_ws,
                              size_t ws_size, hipStream_t stream) {
  const float* x    = (const float*)d_in[0];
  const float* ts   = (const float*)d_in[1];
  const float* si   = (const float*)d_in[2];
  const float* qp   = (const float*)d_in[3];
  const float* pw   = (const float*)d_in[4];
  const float* pb   = (const float*)d_in[5];
  const float* tlw  = (const float*)d_in[6];
  const float* tlb  = (const float*)d_in[7];
  const float* qw   = (const float*)d_in[8];
  const float* qb   = (const float*)d_in[9];
  const float* kw   = (const float*)d_in[10];
  const float* ow   = (const float*)d_in[12];
  const float* ob   = (const float*)d_in[13];
  const float* wih  = (const float*)d_in[14];
  const float* whh  = (const float*)d_in[15];
  const float* bih  = (const float*)d_in[16];
  const float* bhh  = (const float*)d_in[17];
  const float* stw  = (const float*)d_in[18];
  const float* stb  = (const float*)d_in[19];
  const float* c1w  = (const float*)d_in[20];
  const float* c1b  = (const float*)d_in[21];
  const float* bng  = (const float*)d_in[22];
  const float* bnb  = (const float*)d_in[23];
  const float* c2w  = (const float*)d_in[24];
  const float* c2b  = (const float*)d_in[25];
  const int*   rm   = (const int*)d_in[26];

  float* out = (float*)d_out;

  // workspace: 807,168 floats = 3.23 MB (R3 proved >=3.43MB available)
  float* W = (float*)d_ws;
  float* ws_qm2   = W;            // 16384
  float* ws_xmean = W + 16384;    // 2304
  float* ws_hfin  = W + 18688;    // 2048
  float* ws_gis   = W + 20736;    // 786432 (32*128*192)

  hipLaunchKernelGGL(k_pre2, dim3(160), dim3(256), 0, stream,
                     qw, kw, qb, qp, pw, pb, tlw, tlb, x, ws_qm2, ws_xmean,
                     out);
  hipLaunchKernelGGL(k_attn, dim3(B_ * 8), dim3(1024), 0, stream,
                     ws_qm2, ts, pw, pb, tlw, tlb, x, rm, ws_xmean, ow, ob,
                     wih, bih, bhh, ws_gis, out);
  hipLaunchKernelGGL(k_sg, dim3(64), dim3(256), 0, stream,
                     out, ws_gis, whh, bhh, ws_hfin, out);
  hipLaunchKernelGGL(k_cls, dim3(1), dim3(256), 0, stream,
                     ws_hfin, si, stw, stb, c1w, c1b, bng, bnb, c2w, c2b,
                     out);
}

// Round 16
// 246.724 us; speedup vs baseline: 1.0675x; 1.0675x over previous
//
#include <hip/hip_runtime.h>

#define B_   32
#define L_   200
#define DIM_ 36
#define ET_  128
#define NH_  64
#define SD_  9
#define NC_  2

// element offsets within d_out (float32)
#define O_TE   0
#define O_T1   147456
#define O_LG   294912
#define O_SXG  294976
#define O_SOUT 336448
#define O_QP   377920

typedef __fp16 half_t;
typedef __attribute__((ext_vector_type(2))) __fp16 half2_t;

__device__ __forceinline__ float sigm(float x) { return 1.f / (1.f + expf(-x)); }
__device__ __forceinline__ float fsigm(float x) {
  return __builtin_amdgcn_rcpf(1.f + __expf(-x));
}
__device__ __forceinline__ float ftanh(float x) {
  return 2.f * __builtin_amdgcn_rcpf(1.f + __expf(-2.f * x)) - 1.f;
}
__device__ __forceinline__ half2_t f2h2(float a, float b) {
  return __builtin_amdgcn_cvt_pkrtz(a, b);
}
__device__ __forceinline__ float dot2acc(half2_t w, half2_t h, float acc) {
#if __has_builtin(__builtin_amdgcn_fdot2)
  return __builtin_amdgcn_fdot2(w, h, acc, false);
#else
  return acc + (float)w.x * (float)h.x + (float)w.y * (float)h.y;
#endif
}

// ---------------------------------------------------------------------------
// K1 (k_pre2): merged pre + qm2 (R15: worked; saves a launch + M workspace).
//  blocks 0..127: qm2[q] computed directly, no cross-block dep:
//    uq[i] = e_q[q]·qw[i,:] + qb[i]; qm2[q][e] = uq·kw[:,e] / sqrt(128)
//  blocks 128..159: sx_g[b] + xmean[b]  (b = blk-128)
__global__ __launch_bounds__(256) void k_pre2(
    const float* __restrict__ qw, const float* __restrict__ kw,
    const float* __restrict__ qb, const float* __restrict__ qp,
    const float* __restrict__ pw, const float* __restrict__ pb,
    const float* __restrict__ tlw, const float* __restrict__ tlb,
    const float* __restrict__ x, float* __restrict__ qm2,
    float* __restrict__ xmean, float* __restrict__ out) {
  int blk = blockIdx.x, t = threadIdx.x;
  if (blk < 128) {
    __shared__ float eq[128];
    __shared__ float uq[128];
    int q = blk;
    if (t < 128) {
      float tt = qp[q];
      eq[t] = (t == 0) ? tt * tlw[0] + tlb[0]
                       : __sinf(tt * pw[t - 1] + pb[t - 1]);
    }
    __syncthreads();
    if (t < 128) {
      const float4* qw4 = (const float4*)(qw + (size_t)t * 128);
      float a = qb[t];
      #pragma unroll 8
      for (int c = 0; c < 32; c++) {
        float4 w = qw4[c];
        a += eq[4 * c] * w.x + eq[4 * c + 1] * w.y +
             eq[4 * c + 2] * w.z + eq[4 * c + 3] * w.w;
      }
      uq[t] = a;
    }
    __syncthreads();
    if (t < 128) {
      float a = 0.f;
      #pragma unroll 8
      for (int i = 0; i < 128; i++) a += uq[i] * kw[i * 128 + t];
      qm2[q * 128 + t] = a * 0.088388347648318447f;
      if (q == 0) out[O_QP + t] = qp[t];
    }
    return;
  }
  int b = blk - 128;
  __shared__ __align__(16) float sxs[L_][76];
  const float4* xsrc = (const float4*)(x + (size_t)b * L_ * 72);
  for (int idx = t; idx < L_ * 18; idx += 256) {
    int l = idx / 18, c = idx % 18;
    ((float4*)&sxs[l][0])[c] = xsrc[l * 18 + c];
  }
  __syncthreads();
  if (t < 72) {
    float s = 0.f;
    #pragma unroll 8
    for (int l = 0; l < L_; l++) s += sxs[l][t];
    xmean[b * 72 + t] = s * (1.0f / L_);
  }
  for (int idx = t; idx < DIM_ * DIM_; idx += 256) {
    int d = idx / DIM_, e = idx % DIM_;
    float s = 0.f;
    #pragma unroll 8
    for (int l = 0; l < L_; l++) s += sxs[l][d] * sxs[l][e];
    out[O_SXG + (size_t)b * DIM_ * DIM_ + idx] = rintf(sigm(s));
  }
}

// ---------------------------------------------------------------------------
// K2 (k_attn v4, R14 exact): 1024 threads (4 waves/SIMD), latency-hiding
// via occupancy; swizzled key embeddings; f16 W; 4-way l-split sums.
__global__ __launch_bounds__(1024, 1) void k_attn(
    const float* __restrict__ qm, const float* __restrict__ ts,
    const float* __restrict__ pw, const float* __restrict__ pb,
    const float* __restrict__ tlw, const float* __restrict__ tlb,
    const float* __restrict__ x, const int* __restrict__ rm,
    const float* __restrict__ xmean, const float* __restrict__ ow,
    const float* __restrict__ ob, float* __restrict__ out) {
  __shared__ __align__(16) char Abuf[103936];   // ks (f32 swz) / wsh2+sums+ofr
  __shared__ __align__(16) float qs[16][128];
  __shared__ __align__(16) float sc[16][200];
  __shared__ __align__(16) float owsh[DIM_][72];
  float*   ksA  = (float*)Abuf;                       // [200][128] swizzled
  half2_t* wsh2 = (half2_t*)Abuf;                     // [200][72] f16x2
  float*   sums = (float*)(Abuf + 57600);             // [4][16][144] partials
  float*   ofr  = (float*)(Abuf + 57600 + 36864);     // [16][144]

  int b = blockIdx.x >> 3;
  int q0 = (blockIdx.x & 7) << 4;
  int tid = threadIdx.x;

  // P0: stage q-tile, ow, and swizzled key embeddings
  const float4* qsrc = (const float4*)(qm + q0 * ET_);
  for (int i = tid; i < 16 * 32; i += 1024) ((float4*)qs)[i] = qsrc[i];
  const float4* owsrc = (const float4*)ow;
  for (int i = tid; i < DIM_ * 18; i += 1024) ((float4*)owsh)[i] = owsrc[i];
  {
    float tl_w = tlw[0], tl_b = tlb[0];
    const float* tsb = ts + b * L_;
    for (int i = tid; i < L_ * 128; i += 1024) {
      int l = i >> 7, j = i & 127;
      float t = tsb[l];
      float e = (j == 0) ? t * tl_w + tl_b : __sinf(t * pw[j - 1] + pb[j - 1]);
      int blkj = (j >> 2) ^ ((l >> 2) & 7);
      ksA[(l << 7) + (blkj << 2) + (j & 3)] = e;
    }
  }
  __syncthreads();

  // P2: scores -- 16 waves = 8 q-pairs x 2 l-halves; 2 l per lane
  {
    int w = tid >> 6, lg = tid & 63;
    int qp2 = w >> 1;
    int lh = w & 1;
    float acc[2][2];
    #pragma unroll
    for (int i = 0; i < 2; i++)
      #pragma unroll
      for (int j = 0; j < 2; j++) acc[i][j] = 0.f;
    const float4* ks4 = (const float4*)ksA;
    const float4* qs4 = (const float4*)qs;
    int lbase = 100 * lh + 2 * lg;
    int swz0 = (lbase >> 2) & 7;
    int swz1 = ((lbase + 1) >> 2) & 7;
    #pragma unroll 4
    for (int d4 = 0; d4 < 32; d4++) {
      float4 kv[2];
      {
        int l0c = (lbase < 100 * lh + 100) ? lbase : (100 * lh + 99);
        int l1c = (lbase + 1 < 100 * lh + 100) ? lbase + 1 : (100 * lh + 99);
        kv[0] = ks4[(l0c << 5) + (d4 ^ swz0)];
        kv[1] = ks4[(l1c << 5) + (d4 ^ swz1)];
      }
      #pragma unroll
      for (int i = 0; i < 2; i++) {
        float4 qv = qs4[(2 * qp2 + i) * 32 + d4];
        #pragma unroll
        for (int j = 0; j < 2; j++)
          acc[i][j] += qv.x * kv[j].x + qv.y * kv[j].y +
                       qv.z * kv[j].z + qv.w * kv[j].w;
      }
    }
    if (2 * lg < 100) {
      #pragma unroll
      for (int i = 0; i < 2; i++) {
        float2 v = {acc[i][0], acc[i][1]};
        *((float2*)(&sc[2 * qp2 + i][lbase])) = v;
      }
    }
  }
  __syncthreads();

  // P3: rowmax + exp in place (64 lanes per q-row)
  {
    int qi = tid >> 6, li = tid & 63;
    float m = -1e30f;
    for (int l = li; l < L_; l += 64) m = fmaxf(m, sc[qi][l]);
    #pragma unroll
    for (int off = 32; off >= 1; off >>= 1) m = fmaxf(m, __shfl_xor(m, off));
    for (int l = li; l < L_; l += 64) sc[qi][l] = __expf(sc[qi][l] - m);
  }

  // P4: build W f16 into the (dead) ks region
  {
    const float2* xb2 = (const float2*)(x + (size_t)b * L_ * 72);
    const int* rmb = rm + b * L_;
    for (int i = tid; i < L_ * 72; i += 1024) {
      int l = i / 72, c2 = i % 72;
      int seg = c2 / 18, fh = c2 % 18;
      float2 v = xb2[l * 36 + fh];
      float2 o = xb2[l * 36 + 18 + fh];
      float rr = (float)rmb[l];
      float w0, w1;
      if (seg == 0)      { w0 = o.x * v.x;      w1 = o.y * v.y; }
      else if (seg == 1) { w0 = o.x;            w1 = o.y; }
      else if (seg == 2) { w0 = o.x * v.x * rr; w1 = o.y * v.y * rr; }
      else               { w0 = o.x * rr;       w1 = o.y * rr; }
      wsh2[l * 72 + c2] = f2h2(w0, w1);
    }
  }
  __syncthreads();

  // P5: weight sums, l split 4 ways (partials in sums[4][16][144])
  {
    int quarter = tid >> 8, tt = tid & 255;
    int qi = tt >> 4, li = tt & 15;
    int l0 = quarter * 50;
    float accA[8], accB[8];
    #pragma unroll
    for (int k = 0; k < 8; k++) { accA[k] = 0.f; accB[k] = 0.f; }
    const float4* wA = (const float4*)wsh2;
    #pragma unroll 2
    for (int l = l0; l < l0 + 50; l++) {
      float ev = sc[qi][l];
      float4 wa = wA[l * 18 + li];
      union { float f; half2_t h; } u0, u1, u2, u3;
      u0.f = wa.x; u1.f = wa.y; u2.f = wa.z; u3.f = wa.w;
      accA[0] += ev * (float)u0.h.x; accA[1] += ev * (float)u0.h.y;
      accA[2] += ev * (float)u1.h.x; accA[3] += ev * (float)u1.h.y;
      accA[4] += ev * (float)u2.h.x; accA[5] += ev * (float)u2.h.y;
      accA[6] += ev * (float)u3.h.x; accA[7] += ev * (float)u3.h.y;
      if (li < 2) {
        float4 wb = wA[l * 18 + 16 + li];
        union { float f; half2_t h; } b0, b1, b2, b3;
        b0.f = wb.x; b1.f = wb.y; b2.f = wb.z; b3.f = wb.w;
        accB[0] += ev * (float)b0.h.x; accB[1] += ev * (float)b0.h.y;
        accB[2] += ev * (float)b1.h.x; accB[3] += ev * (float)b1.h.y;
        accB[4] += ev * (float)b2.h.x; accB[5] += ev * (float)b2.h.y;
        accB[6] += ev * (float)b3.h.x; accB[7] += ev * (float)b3.h.y;
      }
    }
    float* sq = sums + quarter * 2304 + qi * 144;
    float4* sA = (float4*)(sq + 8 * li);
    sA[0] = make_float4(accA[0], accA[1], accA[2], accA[3]);
    sA[1] = make_float4(accA[4], accA[5], accA[6], accA[7]);
    if (li < 2) {
      float4* sB = (float4*)(sq + 128 + 8 * li);
      sB[0] = make_float4(accB[0], accB[1], accB[2], accB[3]);
      sB[1] = make_float4(accB[4], accB[5], accB[6], accB[7]);
    }
  }
  __syncthreads();

  // P6: combine quarters + divisions + uniform-mean fallback
  const float* xm = xmean + b * 72;
  for (int idx = tid; idx < 16 * DIM_; idx += 1024) {
    int qq = idx / DIM_, j = idx % DIM_;
    const float* s0 = sums + qq * 144;
    const float* s1 = s0 + 2304;
    const float* s2 = s1 + 2304;
    const float* s3 = s2 + 2304;
    float numA = (s0[j] + s1[j]) + (s2[j] + s3[j]);
    float denA = (s0[36 + j] + s1[36 + j]) + (s2[36 + j] + s3[36 + j]);
    float numB = (s0[72 + j] + s1[72 + j]) + (s2[72 + j] + s3[72 + j]);
    float denB = (s0[108 + j] + s1[108 + j]) + (s2[108 + j] + s3[108 + j]);
    float al, ah, bl, bh;
    if (denA > 0.f) { al = numA / denA; ah = 1.f; }
    else            { al = xm[j];       ah = xm[36 + j]; }
    if (denB > 0.f) { bl = numB / denB; bh = 1.f; }
    else            { bl = xm[j];       bh = xm[36 + j]; }
    float* oq = ofr + qq * 144;
    oq[j] = al;      oq[36 + j] = ah;
    oq[72 + j] = bl; oq[108 + j] = bh;
  }
  __syncthreads();

  // P7: output projection (float4 dots)
  for (int idx = tid; idx < 16 * 72; idx += 1024) {
    int qq = idx / 72, t = idx % 72;
    int v = t / DIM_, i2 = t % DIM_;
    const float4* o4 = (const float4*)(ofr + qq * 144 + v * 72);
    const float4* w4 = (const float4*)(owsh[i2]);
    float a = ob[i2];
    #pragma unroll
    for (int d4 = 0; d4 < 18; d4++) {
      float4 ov = o4[d4], wv = w4[d4];
      a += ov.x * wv.x + ov.y * wv.y + ov.z * wv.z + ov.w * wv.w;
    }
    size_t off = ((size_t)b * ET_ + q0 + qq) * DIM_ + i2;
    out[(v == 0 ? O_TE : O_T1) + off] = a;
  }
}

// ---------------------------------------------------------------------------
// K3 (k_sg, R12/R14 exact v6 — best measured 63us): blocks 0..31: sout(b);
// blocks 32..63: GRU v6 (b = blk-32). Phase 1 gi in LDS (R15 lesson: gi
// from global pays the cross-XCD miss toll, +14us); single-wave zero-barrier
// scan with LDS f16 h broadcast (R13 lesson: readlane is 2x worse).
__global__ __launch_bounds__(256, 1) void k_sg(
    const float* __restrict__ out_ro, const float* __restrict__ wih,
    const float* __restrict__ bih, const float* __restrict__ whh,
    const float* __restrict__ bhh, float* __restrict__ hfin,
    float* __restrict__ out) {
  __shared__ __align__(16) float ote_s[ET_][DIM_];  // 18 KB (both branches)
  __shared__ float gis[ET_][3 * NH_];               // 96 KB (gru)
  __shared__ __align__(16) half2_t hpk[NH_ / 2];    // packed f16 h
  int blk = blockIdx.x, t = threadIdx.x;

  if (blk < 32) {
    int b = blk;
    const float4* osrc = (const float4*)(out_ro + O_TE + (size_t)b * ET_ * DIM_);
    for (int idx = t; idx < ET_ * 9; idx += 256)
      ((float4*)&ote_s[0][0])[idx] = osrc[idx];
    __syncthreads();
    for (int idx = t; idx < DIM_ * DIM_; idx += 256) {
      int d = idx / DIM_, e = idx % DIM_;
      float s = 0.f;
      #pragma unroll 8
      for (int q = 0; q < ET_; q++) s += ote_s[q][d] * ote_s[q][e];
      out[O_SOUT + (size_t)b * DIM_ * DIM_ + idx] = sigm(s);
    }
    return;
  }

  int b = blk - 32;
  const float* ote = out_ro + O_TE;
  const float4* osrc = (const float4*)(ote + (size_t)b * ET_ * DIM_);
  for (int idx = t; idx < ET_ * DIM_ / 4; idx += 256)
    ((float4*)&ote_s[0][0])[idx] = osrc[idx];
  __syncthreads();

  // phase 1: gi[q][t] = bih[t] (+bhh[t] for r/z rows) + ote[q]·wih[t]
  if (t < 3 * NH_) {
    float wv[DIM_];
    const float* wrow = wih + (size_t)t * DIM_;
    #pragma unroll
    for (int d = 0; d < DIM_; d++) wv[d] = wrow[d];
    float bi = bih[t] + ((t < 2 * NH_) ? bhh[t] : 0.f);
    for (int q = 0; q < ET_; q++) {
      const float4* xr = (const float4*)ote_s[q];
      float a = bi;
      #pragma unroll
      for (int c = 0; c < 9; c++) {
        float4 xv = xr[c];
        a += xv.x * wv[4 * c] + xv.y * wv[4 * c + 1] +
             xv.z * wv[4 * c + 2] + xv.w * wv[4 * c + 3];
      }
      gis[q][t] = a;
    }
  }
  __syncthreads();
  if (t >= 64) return;  // waves 1..3 exit; wave 0 scans barrier-free

  // pack whh rows t, 64+t, 128+t into f16 (32 half2 each = 96 VGPRs)
  half2_t wr[32], wz[32], wn[32];
  {
    const float2* r0 = (const float2*)(whh + (size_t)t * NH_);
    const float2* r1 = (const float2*)(whh + (size_t)(NH_ + t) * NH_);
    const float2* r2 = (const float2*)(whh + (size_t)(2 * NH_ + t) * NH_);
    #pragma unroll
    for (int c = 0; c < 32; c++) {
      float2 a = r0[c], bb = r1[c], cc = r2[c];
      wr[c] = f2h2(a.x, a.y);
      wz[c] = f2h2(bb.x, bb.y);
      wn[c] = f2h2(cc.x, cc.y);
    }
  }
  float bh_n = bhh[2 * NH_ + t];

  float h = 0.f;
  ((half_t*)hpk)[t] = (half_t)0.f;
  for (int q = 0; q < ET_; q++) {
    float gi_r = gis[q][t];
    float gi_z = gis[q][NH_ + t];
    float gi_n = gis[q][2 * NH_ + t];
    float ar = 0.f, az = 0.f, an = 0.f;
    const float4* hp4 = (const float4*)hpk;
    #pragma unroll
    for (int c4 = 0; c4 < 8; c4++) {
      float4 hv = hp4[c4];  // broadcast b128 (all lanes same addr)
      union { float f; half2_t h; } u0, u1, u2, u3;
      u0.f = hv.x; u1.f = hv.y; u2.f = hv.z; u3.f = hv.w;
      int c = c4 * 4;
      ar = dot2acc(wr[c + 0], u0.h, ar);
      az = dot2acc(wz[c + 0], u0.h, az);
      an = dot2acc(wn[c + 0], u0.h, an);
      ar = dot2acc(wr[c + 1], u1.h, ar);
      az = dot2acc(wz[c + 1], u1.h, az);
      an = dot2acc(wn[c + 1], u1.h, an);
      ar = dot2acc(wr[c + 2], u2.h, ar);
      az = dot2acc(wz[c + 2], u2.h, az);
      an = dot2acc(wn[c + 2], u2.h, an);
      ar = dot2acc(wr[c + 3], u3.h, ar);
      az = dot2acc(wz[c + 3], u3.h, az);
      an = dot2acc(wn[c + 3], u3.h, an);
    }
    float r = fsigm(gi_r + ar);
    float z = fsigm(gi_z + az);
    float n = ftanh(gi_n + r * (an + bh_n));
    h = n + z * (h - n);
    ((half_t*)hpk)[t] = (half_t)h;  // same-wave order: visible next iter
  }
  hfin[b * NH_ + t] = h;
}

// ---------------------------------------------------------------------------
// K4: classifier head: st, concat, c1, batchnorm(batch), gelu, c2 -> logits
__global__ __launch_bounds__(256) void k_cls(
    const float* __restrict__ hfin, const float* __restrict__ si,
    const float* __restrict__ stw, const float* __restrict__ stb,
    const float* __restrict__ c1w, const float* __restrict__ c1b,
    const float* __restrict__ bng, const float* __restrict__ bnb,
    const float* __restrict__ c2w, const float* __restrict__ c2b,
    float* __restrict__ out) {
  __shared__ float cin[B_][72];
  __shared__ float z1[B_][72];
  __shared__ float zg[B_][72];
  int t = threadIdx.x;
  for (int idx = t; idx < B_ * 8; idx += 256) {
    int b = idx / 8, j = idx % 8;
    float acc = stb[j];
    #pragma unroll
    for (int d = 0; d < SD_; d++) acc += si[b * SD_ + d] * stw[j * SD_ + d];
    cin[b][NH_ + j] = acc;
  }
  for (int idx = t; idx < B_ * NH_; idx += 256)
    cin[idx / NH_][idx % NH_] = hfin[idx];
  __syncthreads();
  for (int idx = t; idx < B_ * 72; idx += 256) {
    int b = idx / 72, j = idx % 72;
    float acc = c1b[j];
    #pragma unroll 8
    for (int d = 0; d < 72; d++) acc += cin[b][d] * c1w[j * 72 + d];
    z1[b][j] = acc;
  }
  __syncthreads();
  if (t < 72) {
    float mu = 0.f;
    for (int b = 0; b < B_; b++) mu += z1[b][t];
    mu *= (1.f / B_);
    float vv = 0.f;
    for (int b = 0; b < B_; b++) { float d = z1[b][t] - mu; vv += d * d; }
    vv *= (1.f / B_);
    float inv = 1.f / sqrtf(vv + 1e-5f);
    float g = bng[t], bb = bnb[t];
    for (int b = 0; b < B_; b++) {
      float zn = (z1[b][t] - mu) * inv * g + bb;
      zg[b][t] = 0.5f * zn * (1.f + erff(zn * 0.70710678118654752f));
    }
  }
  __syncthreads();
  for (int idx = t; idx < B_ * NC_; idx += 256) {
    int b = idx / NC_, c = idx % NC_;
    float acc = c2b[c];
    #pragma unroll 8
    for (int d = 0; d < 72; d++) acc += zg[b][d] * c2w[c * 72 + d];
    out[O_LG + idx] = acc;
  }
}

// ---------------------------------------------------------------------------
extern "C" void kernel_launch(void* const* d_in, const int* in_sizes, int n_in,
                              void* d_out, int out_size, void* d_ws,
                              size_t ws_size, hipStream_t stream) {
  const float* x    = (const float*)d_in[0];
  const float* ts   = (const float*)d_in[1];
  const float* si   = (const float*)d_in[2];
  const float* qp   = (const float*)d_in[3];
  const float* pw   = (const float*)d_in[4];
  const float* pb   = (const float*)d_in[5];
  const float* tlw  = (const float*)d_in[6];
  const float* tlb  = (const float*)d_in[7];
  const float* qw   = (const float*)d_in[8];
  const float* qb   = (const float*)d_in[9];
  const float* kw   = (const float*)d_in[10];
  const float* ow   = (const float*)d_in[12];
  const float* ob   = (const float*)d_in[13];
  const float* wih  = (const float*)d_in[14];
  const float* whh  = (const float*)d_in[15];
  const float* bih  = (const float*)d_in[16];
  const float* bhh  = (const float*)d_in[17];
  const float* stw  = (const float*)d_in[18];
  const float* stb  = (const float*)d_in[19];
  const float* c1w  = (const float*)d_in[20];
  const float* c1b  = (const float*)d_in[21];
  const float* bng  = (const float*)d_in[22];
  const float* bnb  = (const float*)d_in[23];
  const float* c2w  = (const float*)d_in[24];
  const float* c2b  = (const float*)d_in[25];
  const int*   rm   = (const int*)d_in[26];

  float* out = (float*)d_out;

  // workspace: 20,736 floats = 83 KB
  float* W = (float*)d_ws;
  float* ws_qm2   = W;            // 16384
  float* ws_xmean = W + 16384;    // 2304
  float* ws_hfin  = W + 18688;    // 2048

  hipLaunchKernelGGL(k_pre2, dim3(160), dim3(256), 0, stream,
                     qw, kw, qb, qp, pw, pb, tlw, tlb, x, ws_qm2, ws_xmean,
                     out);
  hipLaunchKernelGGL(k_attn, dim3(B_ * 8), dim3(1024), 0, stream,
                     ws_qm2, ts, pw, pb, tlw, tlb, x, rm, ws_xmean, ow, ob,
                     out);
  hipLaunchKernelGGL(k_sg, dim3(64), dim3(256), 0, stream,
                     out, wih, bih, whh, bhh, ws_hfin, out);
  hipLaunchKernelGGL(k_cls, dim3(1), dim3(256), 0, stream,
                     ws_hfin, si, stw, stb, c1w, c1b, bng, bnb, c2w, c2b,
                     out);
}

// Round 17
// 231.068 us; speedup vs baseline: 1.1398x; 1.0678x over previous
//
#include <hip/hip_runtime.h>

#define B_   32
#define L_   200
#define DIM_ 36
#define ET_  128
#define NH_  64
#define SD_  9
#define NC_  2

// element offsets within d_out (float32)
#define O_TE   0
#define O_T1   147456
#define O_LG   294912
#define O_SXG  294976
#define O_SOUT 336448
#define O_QP   377920

typedef __fp16 half_t;
typedef __attribute__((ext_vector_type(2))) __fp16 half2_t;

__device__ __forceinline__ float sigm(float x) { return 1.f / (1.f + expf(-x)); }
__device__ __forceinline__ float fsigm(float x) {
  return __builtin_amdgcn_rcpf(1.f + __expf(-x));
}
__device__ __forceinline__ float ftanh(float x) {
  return 2.f * __builtin_amdgcn_rcpf(1.f + __expf(-2.f * x)) - 1.f;
}
__device__ __forceinline__ half2_t f2h2(float a, float b) {
  return __builtin_amdgcn_cvt_pkrtz(a, b);
}
__device__ __forceinline__ float dot2acc(half2_t w, half2_t h, float acc) {
#if __has_builtin(__builtin_amdgcn_fdot2)
  return __builtin_amdgcn_fdot2(w, h, acc, false);
#else
  return acc + (float)w.x * (float)h.x + (float)w.y * (float)h.y;
#endif
}

// ---------------------------------------------------------------------------
// K1 (k_pre2 v2): sxg moved OUT (to k_sg's sout blocks, hidden under the gru
// scan). blocks 0..127: qm2[q]; blocks 128..159: xmean[b] only (no LDS).
__global__ __launch_bounds__(256) void k_pre2(
    const float* __restrict__ qw, const float* __restrict__ kw,
    const float* __restrict__ qb, const float* __restrict__ qp,
    const float* __restrict__ pw, const float* __restrict__ pb,
    const float* __restrict__ tlw, const float* __restrict__ tlb,
    const float* __restrict__ x, float* __restrict__ qm2,
    float* __restrict__ xmean, float* __restrict__ out) {
  int blk = blockIdx.x, t = threadIdx.x;
  if (blk < 128) {
    __shared__ float eq[128];
    __shared__ float uq[128];
    int q = blk;
    if (t < 128) {
      float tt = qp[q];
      eq[t] = (t == 0) ? tt * tlw[0] + tlb[0]
                       : __sinf(tt * pw[t - 1] + pb[t - 1]);
    }
    __syncthreads();
    if (t < 128) {
      const float4* qw4 = (const float4*)(qw + (size_t)t * 128);
      float a = qb[t];
      #pragma unroll 8
      for (int c = 0; c < 32; c++) {
        float4 w = qw4[c];
        a += eq[4 * c] * w.x + eq[4 * c + 1] * w.y +
             eq[4 * c + 2] * w.z + eq[4 * c + 3] * w.w;
      }
      uq[t] = a;
    }
    __syncthreads();
    if (t < 128) {
      float a = 0.f;
      #pragma unroll 8
      for (int i = 0; i < 128; i++) a += uq[i] * kw[i * 128 + t];
      qm2[q * 128 + t] = a * 0.088388347648318447f;
      if (q == 0) out[O_QP + t] = qp[t];
    }
    return;
  }
  // xmean only: coalesced global reads (lanes d consecutive)
  int b = blk - 128;
  if (t < 72) {
    float s = 0.f;
    const float* xb = x + (size_t)b * L_ * 72 + t;
    #pragma unroll 8
    for (int l = 0; l < L_; l++) s += xb[(size_t)l * 72];
    xmean[b * 72 + t] = s * (1.0f / L_);
  }
}

// ---------------------------------------------------------------------------
// K2 (k_attn v4, R14/R16 exact): 1024 threads (4 waves/SIMD).
__global__ __launch_bounds__(1024, 1) void k_attn(
    const float* __restrict__ qm, const float* __restrict__ ts,
    const float* __restrict__ pw, const float* __restrict__ pb,
    const float* __restrict__ tlw, const float* __restrict__ tlb,
    const float* __restrict__ x, const int* __restrict__ rm,
    const float* __restrict__ xmean, const float* __restrict__ ow,
    const float* __restrict__ ob, float* __restrict__ out) {
  __shared__ __align__(16) char Abuf[103936];   // ks (f32 swz) / wsh2+sums+ofr
  __shared__ __align__(16) float qs[16][128];
  __shared__ __align__(16) float sc[16][200];
  __shared__ __align__(16) float owsh[DIM_][72];
  float*   ksA  = (float*)Abuf;                       // [200][128] swizzled
  half2_t* wsh2 = (half2_t*)Abuf;                     // [200][72] f16x2
  float*   sums = (float*)(Abuf + 57600);             // [4][16][144] partials
  float*   ofr  = (float*)(Abuf + 57600 + 36864);     // [16][144]

  int b = blockIdx.x >> 3;
  int q0 = (blockIdx.x & 7) << 4;
  int tid = threadIdx.x;

  // P0: stage q-tile, ow, and swizzled key embeddings
  const float4* qsrc = (const float4*)(qm + q0 * ET_);
  for (int i = tid; i < 16 * 32; i += 1024) ((float4*)qs)[i] = qsrc[i];
  const float4* owsrc = (const float4*)ow;
  for (int i = tid; i < DIM_ * 18; i += 1024) ((float4*)owsh)[i] = owsrc[i];
  {
    float tl_w = tlw[0], tl_b = tlb[0];
    const float* tsb = ts + b * L_;
    for (int i = tid; i < L_ * 128; i += 1024) {
      int l = i >> 7, j = i & 127;
      float t = tsb[l];
      float e = (j == 0) ? t * tl_w + tl_b : __sinf(t * pw[j - 1] + pb[j - 1]);
      int blkj = (j >> 2) ^ ((l >> 2) & 7);
      ksA[(l << 7) + (blkj << 2) + (j & 3)] = e;
    }
  }
  __syncthreads();

  // P2: scores -- 16 waves = 8 q-pairs x 2 l-halves; 2 l per lane
  {
    int w = tid >> 6, lg = tid & 63;
    int qp2 = w >> 1;
    int lh = w & 1;
    float acc[2][2];
    #pragma unroll
    for (int i = 0; i < 2; i++)
      #pragma unroll
      for (int j = 0; j < 2; j++) acc[i][j] = 0.f;
    const float4* ks4 = (const float4*)ksA;
    const float4* qs4 = (const float4*)qs;
    int lbase = 100 * lh + 2 * lg;
    int swz0 = (lbase >> 2) & 7;
    int swz1 = ((lbase + 1) >> 2) & 7;
    #pragma unroll 4
    for (int d4 = 0; d4 < 32; d4++) {
      float4 kv[2];
      {
        int l0c = (lbase < 100 * lh + 100) ? lbase : (100 * lh + 99);
        int l1c = (lbase + 1 < 100 * lh + 100) ? lbase + 1 : (100 * lh + 99);
        kv[0] = ks4[(l0c << 5) + (d4 ^ swz0)];
        kv[1] = ks4[(l1c << 5) + (d4 ^ swz1)];
      }
      #pragma unroll
      for (int i = 0; i < 2; i++) {
        float4 qv = qs4[(2 * qp2 + i) * 32 + d4];
        #pragma unroll
        for (int j = 0; j < 2; j++)
          acc[i][j] += qv.x * kv[j].x + qv.y * kv[j].y +
                       qv.z * kv[j].z + qv.w * kv[j].w;
      }
    }
    if (2 * lg < 100) {
      #pragma unroll
      for (int i = 0; i < 2; i++) {
        float2 v = {acc[i][0], acc[i][1]};
        *((float2*)(&sc[2 * qp2 + i][lbase])) = v;
      }
    }
  }
  __syncthreads();

  // P3: rowmax + exp in place (64 lanes per q-row)
  {
    int qi = tid >> 6, li = tid & 63;
    float m = -1e30f;
    for (int l = li; l < L_; l += 64) m = fmaxf(m, sc[qi][l]);
    #pragma unroll
    for (int off = 32; off >= 1; off >>= 1) m = fmaxf(m, __shfl_xor(m, off));
    for (int l = li; l < L_; l += 64) sc[qi][l] = __expf(sc[qi][l] - m);
  }

  // P4: build W f16 into the (dead) ks region
  {
    const float2* xb2 = (const float2*)(x + (size_t)b * L_ * 72);
    const int* rmb = rm + b * L_;
    for (int i = tid; i < L_ * 72; i += 1024) {
      int l = i / 72, c2 = i % 72;
      int seg = c2 / 18, fh = c2 % 18;
      float2 v = xb2[l * 36 + fh];
      float2 o = xb2[l * 36 + 18 + fh];
      float rr = (float)rmb[l];
      float w0, w1;
      if (seg == 0)      { w0 = o.x * v.x;      w1 = o.y * v.y; }
      else if (seg == 1) { w0 = o.x;            w1 = o.y; }
      else if (seg == 2) { w0 = o.x * v.x * rr; w1 = o.y * v.y * rr; }
      else               { w0 = o.x * rr;       w1 = o.y * rr; }
      wsh2[l * 72 + c2] = f2h2(w0, w1);
    }
  }
  __syncthreads();

  // P5: weight sums, l split 4 ways (partials in sums[4][16][144])
  {
    int quarter = tid >> 8, tt = tid & 255;
    int qi = tt >> 4, li = tt & 15;
    int l0 = quarter * 50;
    float accA[8], accB[8];
    #pragma unroll
    for (int k = 0; k < 8; k++) { accA[k] = 0.f; accB[k] = 0.f; }
    const float4* wA = (const float4*)wsh2;
    #pragma unroll 2
    for (int l = l0; l < l0 + 50; l++) {
      float ev = sc[qi][l];
      float4 wa = wA[l * 18 + li];
      union { float f; half2_t h; } u0, u1, u2, u3;
      u0.f = wa.x; u1.f = wa.y; u2.f = wa.z; u3.f = wa.w;
      accA[0] += ev * (float)u0.h.x; accA[1] += ev * (float)u0.h.y;
      accA[2] += ev * (float)u1.h.x; accA[3] += ev * (float)u1.h.y;
      accA[4] += ev * (float)u2.h.x; accA[5] += ev * (float)u2.h.y;
      accA[6] += ev * (float)u3.h.x; accA[7] += ev * (float)u3.h.y;
      if (li < 2) {
        float4 wb = wA[l * 18 + 16 + li];
        union { float f; half2_t h; } b0, b1, b2, b3;
        b0.f = wb.x; b1.f = wb.y; b2.f = wb.z; b3.f = wb.w;
        accB[0] += ev * (float)b0.h.x; accB[1] += ev * (float)b0.h.y;
        accB[2] += ev * (float)b1.h.x; accB[3] += ev * (float)b1.h.y;
        accB[4] += ev * (float)b2.h.x; accB[5] += ev * (float)b2.h.y;
        accB[6] += ev * (float)b3.h.x; accB[7] += ev * (float)b3.h.y;
      }
    }
    float* sq = sums + quarter * 2304 + qi * 144;
    float4* sA = (float4*)(sq + 8 * li);
    sA[0] = make_float4(accA[0], accA[1], accA[2], accA[3]);
    sA[1] = make_float4(accA[4], accA[5], accA[6], accA[7]);
    if (li < 2) {
      float4* sB = (float4*)(sq + 128 + 8 * li);
      sB[0] = make_float4(accB[0], accB[1], accB[2], accB[3]);
      sB[1] = make_float4(accB[4], accB[5], accB[6], accB[7]);
    }
  }
  __syncthreads();

  // P6: combine quarters + divisions + uniform-mean fallback
  const float* xm = xmean + b * 72;
  for (int idx = tid; idx < 16 * DIM_; idx += 1024) {
    int qq = idx / DIM_, j = idx % DIM_;
    const float* s0 = sums + qq * 144;
    const float* s1 = s0 + 2304;
    const float* s2 = s1 + 2304;
    const float* s3 = s2 + 2304;
    float numA = (s0[j] + s1[j]) + (s2[j] + s3[j]);
    float denA = (s0[36 + j] + s1[36 + j]) + (s2[36 + j] + s3[36 + j]);
    float numB = (s0[72 + j] + s1[72 + j]) + (s2[72 + j] + s3[72 + j]);
    float denB = (s0[108 + j] + s1[108 + j]) + (s2[108 + j] + s3[108 + j]);
    float al, ah, bl, bh;
    if (denA > 0.f) { al = numA / denA; ah = 1.f; }
    else            { al = xm[j];       ah = xm[36 + j]; }
    if (denB > 0.f) { bl = numB / denB; bh = 1.f; }
    else            { bl = xm[j];       bh = xm[36 + j]; }
    float* oq = ofr + qq * 144;
    oq[j] = al;      oq[36 + j] = ah;
    oq[72 + j] = bl; oq[108 + j] = bh;
  }
  __syncthreads();

  // P7: output projection (float4 dots)
  for (int idx = tid; idx < 16 * 72; idx += 1024) {
    int qq = idx / 72, t = idx % 72;
    int v = t / DIM_, i2 = t % DIM_;
    const float4* o4 = (const float4*)(ofr + qq * 144 + v * 72);
    const float4* w4 = (const float4*)(owsh[i2]);
    float a = ob[i2];
    #pragma unroll
    for (int d4 = 0; d4 < 18; d4++) {
      float4 ov = o4[d4], wv = w4[d4];
      a += ov.x * wv.x + ov.y * wv.y + ov.z * wv.z + ov.w * wv.w;
    }
    size_t off = ((size_t)b * ET_ + q0 + qq) * DIM_ + i2;
    out[(v == 0 ? O_TE : O_T1) + off] = a;
  }
}

// ---------------------------------------------------------------------------
// K3 (k_sg): blocks 0..31: sout(b) + sxg(b) — sxg moved here from k_pre2,
// HIDDEN under the gru scan (sout+sxg ~27us << scan 63us; those CUs idled).
// blocks 32..63: GRU v6 (R12/R16 exact — best measured).
__global__ __launch_bounds__(256, 1) void k_sg(
    const float* __restrict__ out_ro, const float* __restrict__ x,
    const float* __restrict__ wih, const float* __restrict__ bih,
    const float* __restrict__ whh, const float* __restrict__ bhh,
    float* __restrict__ hfin, float* __restrict__ out) {
  __shared__ __align__(16) float ote_s[ET_][DIM_];  // 18 KB (both branches)
  __shared__ float gis[ET_][3 * NH_];               // 96 KB (gru / sxg stage)
  __shared__ __align__(16) half2_t hpk[NH_ / 2];    // packed f16 h
  int blk = blockIdx.x, t = threadIdx.x;

  if (blk < 32) {
    int b = blk;
    // stage out_te[b] and x[b] (sxs in the gis region, stride 76)
    float* sxs = (float*)gis;  // [200][76]
    const float4* osrc = (const float4*)(out_ro + O_TE + (size_t)b * ET_ * DIM_);
    for (int idx = t; idx < ET_ * 9; idx += 256)
      ((float4*)&ote_s[0][0])[idx] = osrc[idx];
    const float4* xsrc = (const float4*)(x + (size_t)b * L_ * 72);
    for (int idx = t; idx < L_ * 18; idx += 256) {
      int l = idx / 18, c = idx % 18;
      ((float4*)&sxs[l * 76])[c] = xsrc[idx];
    }
    __syncthreads();
    for (int idx = t; idx < DIM_ * DIM_; idx += 256) {
      int d = idx / DIM_, e = idx % DIM_;
      float s = 0.f;
      #pragma unroll 8
      for (int q = 0; q < ET_; q++) s += ote_s[q][d] * ote_s[q][e];
      out[O_SOUT + (size_t)b * DIM_ * DIM_ + idx] = sigm(s);
    }
    for (int idx = t; idx < DIM_ * DIM_; idx += 256) {
      int d = idx / DIM_, e = idx % DIM_;
      float s = 0.f;
      #pragma unroll 8
      for (int l = 0; l < L_; l++) s += sxs[l * 76 + d] * sxs[l * 76 + e];
      out[O_SXG + (size_t)b * DIM_ * DIM_ + idx] = rintf(sigm(s));
    }
    return;
  }

  int b = blk - 32;
  const float* ote = out_ro + O_TE;
  const float4* osrc = (const float4*)(ote + (size_t)b * ET_ * DIM_);
  for (int idx = t; idx < ET_ * DIM_ / 4; idx += 256)
    ((float4*)&ote_s[0][0])[idx] = osrc[idx];
  __syncthreads();

  // phase 1: gi[q][t] = bih[t] (+bhh[t] for r/z rows) + ote[q]·wih[t]
  if (t < 3 * NH_) {
    float wv[DIM_];
    const float* wrow = wih + (size_t)t * DIM_;
    #pragma unroll
    for (int d = 0; d < DIM_; d++) wv[d] = wrow[d];
    float bi = bih[t] + ((t < 2 * NH_) ? bhh[t] : 0.f);
    for (int q = 0; q < ET_; q++) {
      const float4* xr = (const float4*)ote_s[q];
      float a = bi;
      #pragma unroll
      for (int c = 0; c < 9; c++) {
        float4 xv = xr[c];
        a += xv.x * wv[4 * c] + xv.y * wv[4 * c + 1] +
             xv.z * wv[4 * c + 2] + xv.w * wv[4 * c + 3];
      }
      gis[q][t] = a;
    }
  }
  __syncthreads();
  if (t >= 64) return;  // waves 1..3 exit; wave 0 scans barrier-free

  // pack whh rows t, 64+t, 128+t into f16 (32 half2 each = 96 VGPRs)
  half2_t wr[32], wz[32], wn[32];
  {
    const float2* r0 = (const float2*)(whh + (size_t)t * NH_);
    const float2* r1 = (const float2*)(whh + (size_t)(NH_ + t) * NH_);
    const float2* r2 = (const float2*)(whh + (size_t)(2 * NH_ + t) * NH_);
    #pragma unroll
    for (int c = 0; c < 32; c++) {
      float2 a = r0[c], bb = r1[c], cc = r2[c];
      wr[c] = f2h2(a.x, a.y);
      wz[c] = f2h2(bb.x, bb.y);
      wn[c] = f2h2(cc.x, cc.y);
    }
  }
  float bh_n = bhh[2 * NH_ + t];

  float h = 0.f;
  ((half_t*)hpk)[t] = (half_t)0.f;
  for (int q = 0; q < ET_; q++) {
    float gi_r = gis[q][t];
    float gi_z = gis[q][NH_ + t];
    float gi_n = gis[q][2 * NH_ + t];
    float ar = 0.f, az = 0.f, an = 0.f;
    const float4* hp4 = (const float4*)hpk;
    #pragma unroll
    for (int c4 = 0; c4 < 8; c4++) {
      float4 hv = hp4[c4];  // broadcast b128 (all lanes same addr)
      union { float f; half2_t h; } u0, u1, u2, u3;
      u0.f = hv.x; u1.f = hv.y; u2.f = hv.z; u3.f = hv.w;
      int c = c4 * 4;
      ar = dot2acc(wr[c + 0], u0.h, ar);
      az = dot2acc(wz[c + 0], u0.h, az);
      an = dot2acc(wn[c + 0], u0.h, an);
      ar = dot2acc(wr[c + 1], u1.h, ar);
      az = dot2acc(wz[c + 1], u1.h, az);
      an = dot2acc(wn[c + 1], u1.h, an);
      ar = dot2acc(wr[c + 2], u2.h, ar);
      az = dot2acc(wz[c + 2], u2.h, az);
      an = dot2acc(wn[c + 2], u2.h, an);
      ar = dot2acc(wr[c + 3], u3.h, ar);
      az = dot2acc(wz[c + 3], u3.h, az);
      an = dot2acc(wn[c + 3], u3.h, an);
    }
    float r = fsigm(gi_r + ar);
    float z = fsigm(gi_z + az);
    float n = ftanh(gi_n + r * (an + bh_n));
    h = n + z * (h - n);
    ((half_t*)hpk)[t] = (half_t)h;  // same-wave order: visible next iter
  }
  hfin[b * NH_ + t] = h;
}

// ---------------------------------------------------------------------------
// K4: classifier head: st, concat, c1, batchnorm(batch), gelu, c2 -> logits
__global__ __launch_bounds__(256) void k_cls(
    const float* __restrict__ hfin, const float* __restrict__ si,
    const float* __restrict__ stw, const float* __restrict__ stb,
    const float* __restrict__ c1w, const float* __restrict__ c1b,
    const float* __restrict__ bng, const float* __restrict__ bnb,
    const float* __restrict__ c2w, const float* __restrict__ c2b,
    float* __restrict__ out) {
  __shared__ float cin[B_][72];
  __shared__ float z1[B_][72];
  __shared__ float zg[B_][72];
  int t = threadIdx.x;
  for (int idx = t; idx < B_ * 8; idx += 256) {
    int b = idx / 8, j = idx % 8;
    float acc = stb[j];
    #pragma unroll
    for (int d = 0; d < SD_; d++) acc += si[b * SD_ + d] * stw[j * SD_ + d];
    cin[b][NH_ + j] = acc;
  }
  for (int idx = t; idx < B_ * NH_; idx += 256)
    cin[idx / NH_][idx % NH_] = hfin[idx];
  __syncthreads();
  for (int idx = t; idx < B_ * 72; idx += 256) {
    int b = idx / 72, j = idx % 72;
    float acc = c1b[j];
    #pragma unroll 8
    for (int d = 0; d < 72; d++) acc += cin[b][d] * c1w[j * 72 + d];
    z1[b][j] = acc;
  }
  __syncthreads();
  if (t < 72) {
    float mu = 0.f;
    for (int b = 0; b < B_; b++) mu += z1[b][t];
    mu *= (1.f / B_);
    float vv = 0.f;
    for (int b = 0; b < B_; b++) { float d = z1[b][t] - mu; vv += d * d; }
    vv *= (1.f / B_);
    float inv = 1.f / sqrtf(vv + 1e-5f);
    float g = bng[t], bb = bnb[t];
    for (int b = 0; b < B_; b++) {
      float zn = (z1[b][t] - mu) * inv * g + bb;
      zg[b][t] = 0.5f * zn * (1.f + erff(zn * 0.70710678118654752f));
    }
  }
  __syncthreads();
  for (int idx = t; idx < B_ * NC_; idx += 256) {
    int b = idx / NC_, c = idx % NC_;
    float acc = c2b[c];
    #pragma unroll 8
    for (int d = 0; d < 72; d++) acc += zg[b][d] * c2w[c * 72 + d];
    out[O_LG + idx] = acc;
  }
}

// ---------------------------------------------------------------------------
extern "C" void kernel_launch(void* const* d_in, const int* in_sizes, int n_in,
                              void* d_out, int out_size, void* d_ws,
                              size_t ws_size, hipStream_t stream) {
  const float* x    = (const float*)d_in[0];
  const float* ts   = (const float*)d_in[1];
  const float* si   = (const float*)d_in[2];
  const float* qp   = (const float*)d_in[3];
  const float* pw   = (const float*)d_in[4];
  const float* pb   = (const float*)d_in[5];
  const float* tlw  = (const float*)d_in[6];
  const float* tlb  = (const float*)d_in[7];
  const float* qw   = (const float*)d_in[8];
  const float* qb   = (const float*)d_in[9];
  const float* kw   = (const float*)d_in[10];
  const float* ow   = (const float*)d_in[12];
  const float* ob   = (const float*)d_in[13];
  const float* wih  = (const float*)d_in[14];
  const float* whh  = (const float*)d_in[15];
  const float* bih  = (const float*)d_in[16];
  const float* bhh  = (const float*)d_in[17];
  const float* stw  = (const float*)d_in[18];
  const float* stb  = (const float*)d_in[19];
  const float* c1w  = (const float*)d_in[20];
  const float* c1b  = (const float*)d_in[21];
  const float* bng  = (const float*)d_in[22];
  const float* bnb  = (const float*)d_in[23];
  const float* c2w  = (const float*)d_in[24];
  const float* c2b  = (const float*)d_in[25];
  const int*   rm   = (const int*)d_in[26];

  float* out = (float*)d_out;

  // workspace: 20,736 floats = 83 KB
  float* W = (float*)d_ws;
  float* ws_qm2   = W;            // 16384
  float* ws_xmean = W + 16384;    // 2304
  float* ws_hfin  = W + 18688;    // 2048

  hipLaunchKernelGGL(k_pre2, dim3(160), dim3(256), 0, stream,
                     qw, kw, qb, qp, pw, pb, tlw, tlb, x, ws_qm2, ws_xmean,
                     out);
  hipLaunchKernelGGL(k_attn, dim3(B_ * 8), dim3(1024), 0, stream,
                     ws_qm2, ts, pw, pb, tlw, tlb, x, rm, ws_xmean, ow, ob,
                     out);
  hipLaunchKernelGGL(k_sg, dim3(64), dim3(256), 0, stream,
                     out, x, wih, bih, whh, bhh, ws_hfin, out);
  hipLaunchKernelGGL(k_cls, dim3(1), dim3(256), 0, stream,
                     ws_hfin, si, stw, stb, c1w, c1b, bng, bnb, c2w, c2b,
                     out);
}